// Round 3
// baseline (6454.210 us; speedup 1.0000x reference)
//
#include <hip/hip_runtime.h>
#include <hip/hip_cooperative_groups.h>
#include <math.h>

#define T_   32
#define N_   64
#define NL   64
#define E_   128
#define G3   384   // 3*E
#define NE   4
#define CH   64
#define D_   16
#define HW   16
#define RH   64
#define LE   64
#define HD   512
#define A_   16
#define INVN 32
#define KCOLS 9216 // CH*D_*3*3
#define OUTW 663

__device__ __forceinline__ float sigf(float x) { return 1.f/(1.f+expf(-x)); }

// ---------------- prep kernels ----------------

__global__ __launch_bounds__(128) void k_prep_M(const int* lines, const float* emb_task, float* M) {
    int nl = blockIdx.x;
    int i  = threadIdx.x;
    const int* ln = lines + nl*4;
    float s = 0.f;
    #pragma unroll
    for (int t = 0; t < 4; ++t) s += emb_task[ln[t]*E_ + i];
    M[nl*E_ + i] = s;
}

// T4[((dir*32 + k/4)*384 + g)*4 + (k%4)] = w[dir][g*128+k]
__global__ __launch_bounds__(128) void k_prep_T4(const float* wif, const float* wib,
                                                 const float* whf, const float* whb,
                                                 float* wiT4, float* whT4) {
    int g = blockIdx.x % 384, dir = blockIdx.x / 384;
    int k = threadIdx.x;
    const float* wi = dir ? wib : wif;
    const float* wh = dir ? whb : whf;
    int dst = ((dir*32 + (k>>2))*384 + g)*4 + (k&3);
    wiT4[dst] = wi[g*128 + k];
    whT4[dst] = wh[g*128 + k];
}

__global__ __launch_bounds__(128) void k_prep_misc(const int* p0, const float* M, int* p_cur, float* mp) {
    int n = blockIdx.x, i = threadIdx.x;
    int p = p0[n];
    if (i == 0) p_cur[n] = p;
    mp[n*E_ + i] = M[(n*NL + p)*E_ + i];
}

__global__ __launch_bounds__(64) void k_prep_invpa(const float* inv, const float* inv_w, const float* inv_b,
                                                   const int* pa, const float* emb_lower,
                                                   float* inv_all, float* pa_all) {
    int tn = blockIdx.x, r = threadIdx.x;
    const float* iv = inv + tn*INVN;
    float acc = inv_b[r];
    #pragma unroll
    for (int i = 0; i < INVN; ++i) acc += iv[i]*inv_w[i*RH + r];
    inv_all[tn*RH + r] = fmaxf(acc, 0.f);
    const int* pp = pa + tn*4;
    float s = 0.f;
    #pragma unroll
    for (int j = 0; j < 4; ++j) s += emb_lower[pp[j]*LE + r];
    pa_all[tn*LE + r] = s;
}

// giM[dir][n][l][g] = M[n][l] . wi[g] + bi[g]
__global__ __launch_bounds__(384) void k_giM(const float* M, const float* wiT4,
                                             const float* bif, const float* bib, float* giM) {
    int lblk = blockIdx.x, n = blockIdx.y, dir = blockIdx.z;
    int g = threadIdx.x;
    __shared__ float Ml[8][E_];
    for (int idx = g; idx < 8*E_; idx += 384) {
        int r = idx >> 7, k = idx & 127;
        Ml[r][k] = M[(n*NL + lblk*8 + r)*E_ + k];
    }
    __syncthreads();
    float acc[8];
    #pragma unroll
    for (int r = 0; r < 8; ++r) acc[r] = 0.f;
    const float4* W = (const float4*)(wiT4) + dir*32*384;
    for (int kq = 0; kq < 32; ++kq) {
        float4 w = W[kq*384 + g];
        #pragma unroll
        for (int r = 0; r < 8; ++r) {
            float4 h = *(const float4*)&Ml[r][kq*4];
            acc[r] += w.x*h.x + w.y*h.y + w.z*h.z + w.w*h.w;
        }
    }
    float bi = dir ? bib[g] : bif[g];
    #pragma unroll
    for (int r = 0; r < 8; ++r)
        giM[((dir*N_ + n)*NL + lblk*8 + r)*G3 + g] = acc[r] + bi;
}

// GRU over all rolls. grid (pblk 4, n 64, dir 2) = 512 wgs, 256 thr.
// 16 sequences per wg; thread: i = tid&127 (hidden idx), sb = tid>>7 (8 seqs each).
__global__ __launch_bounds__(256) void k_gru(const float* giM, const float* whT4,
                                             const float* bhf, const float* bhb,
                                             const float* beta_w, const float* beta_b,
                                             float* Ball) {
    int pblk = blockIdx.x, n = blockIdx.y, dir = blockIdx.z;
    int tid = threadIdx.x;
    int i = tid & 127;
    int sb = tid >> 7;

    __shared__ float Hs[16][132];
    __shared__ float bwT[NE][132];      // transposed beta weights (conflict-free reads)
    for (int idx = tid; idx < 16*132; idx += 256) ((float*)Hs)[idx] = 0.f;
    for (int idx = tid; idx < E_*NE; idx += 256) {
        int k = idx >> 2, e = idx & 3;
        bwT[e][k] = beta_w[k*NE + e];
    }
    const float* bh = dir ? bhb : bhf;
    float bhr = bh[i], bhz = bh[128+i], bhn = bh[256+i];
    const float4* W = (const float4*)(whT4) + dir*32*384;
    const float* giBase = giM + (dir*N_ + n)*NL*G3;
    // beta-head thread mapping (all 256 threads)
    int bs = tid >> 4;          // seq 0..15
    int bpart = (tid >> 2) & 3; // k-quarter
    int be = tid & 3;           // expert
    float bbias = beta_b[be];
    __syncthreads();

    for (int j = 0; j < NL; ++j) {
        float accr[8], accz[8], accn[8];
        #pragma unroll
        for (int s = 0; s < 8; ++s) { accr[s]=bhr; accz[s]=bhz; accn[s]=bhn; }
        #pragma unroll 2
        for (int kq = 0; kq < 32; ++kq) {
            float4 wr = W[kq*384 + i];
            float4 wz = W[kq*384 + 128 + i];
            float4 wn = W[kq*384 + 256 + i];
            #pragma unroll
            for (int s = 0; s < 8; ++s) {
                float4 h = *(const float4*)&Hs[sb*8 + s][kq*4];
                accr[s] += wr.x*h.x + wr.y*h.y + wr.z*h.z + wr.w*h.w;
                accz[s] += wz.x*h.x + wz.y*h.y + wz.z*h.z + wz.w*h.w;
                accn[s] += wn.x*h.x + wn.y*h.y + wn.z*h.z + wn.w*h.w;
            }
        }
        float hnew[8];
        #pragma unroll
        for (int s = 0; s < 8; ++s) {
            int ss = sb*8 + s;
            int p  = pblk*16 + ss;
            int l  = dir ? ((p + 63 - j) & 63) : ((p + j) & 63);
            const float* gi = giBase + l*G3;
            float r  = sigf(gi[i]       + accr[s]);
            float z  = sigf(gi[128+i]   + accz[s]);
            float nn = tanhf(gi[256+i]  + r*accn[s]);
            hnew[s] = (1.f - z)*nn + z*Hs[ss][i];
        }
        __syncthreads();
        #pragma unroll
        for (int s = 0; s < 8; ++s) Hs[sb*8 + s][i] = hnew[s];
        __syncthreads();
        // beta head: 16 seqs x 4 e x 4 k-parts, bpart-rotated to avoid bank conflicts
        {
            float acc = 0.f;
            const float* hrow = &Hs[bs][0];
            const float* brow = &bwT[be][0];
            #pragma unroll 8
            for (int k = 0; k < 32; ++k) {
                int k2 = bpart*32 + ((k + bpart*8) & 31);
                acc += hrow[k2]*brow[k2];
            }
            acc += __shfl_xor(acc, 4);
            acc += __shfl_xor(acc, 8);
            if (bpart == 0) {
                float bval = sigf(acc + bbias);
                int p = pblk*16 + bs;
                int j2 = 2*j + dir;
                Ball[((n*NL + p)*128 + j2)*NE + be] = bval;
            }
        }
    }
}

// stick-breaking -> reordered P_final[n][p][j][e]
__global__ __launch_bounds__(64) void k_P(const float* Ball, float* Pall) {
    int np = blockIdx.x;
    int tid = threadIdx.x;
    __shared__ float B[128][NE];
    __shared__ float Pf[128][NE];
    const float* src = Ball + np*128*NE;
    for (int idx = tid; idx < 128*NE; idx += 64) ((float*)B)[idx] = src[idx];
    __syncthreads();
    if (tid < NE) {
        int e = tid;
        float c = 1.f;
        for (int j2 = 0; j2 < 128; ++j2) {
            float bz = (j2 == 0 || j2 == 127) ? 0.f : B[j2][e];
            float bf = (j2 == 127) ? 1.f : bz;
            Pf[j2][e] = bf * c;
            c *= (1.f - bz);
        }
    }
    __syncthreads();
    float* dst = Pall + np*128*NE;
    for (int idx = tid; idx < 128*NE; idx += 64) {
        int j = idx >> 2, e = idx & 3;
        int jf = (j < 64) ? (2*(63 - j) + 1) : (2*(j - 64));
        dst[idx] = Pf[jf][e];
    }
}

// ---------------- cooperative T-loop ----------------
// grid 256 wgs x 256 thr. Per step:
//   A (wg<144): kern_buf[n][col] = mp[n].kernel_w[:,col]+b   (64 cols/wg, all n)
//   B (all 256 = 4 quarters x 64 n): conv 16 channels -> h1_buf
//   C (wg<64): heads, dsel, p_cur/mp update, out writes
__global__ __launch_bounds__(256) void k_loop(
    const float* obs, const float* kernel_w, const float* kernel_b, const float* conv_bias,
    const float* amask, const float* Pall, const float* M,
    const float* inv_all, const float* pa_all,
    const float* zw, const float* zb, const float* aw, const float* ab,
    const float* uw, const float* ub, const float* dw, const float* db,
    const float* cw, const float* cb,
    float* kern_buf, float* h1_buf, float* mp_buf, int* p_cur, float* out) {

    cooperative_groups::grid_group grid = cooperative_groups::this_grid();
    const int wg  = blockIdx.x;
    const int tid = threadIdx.x;

    __shared__ float mpT[E_*66];          // phase A: mp transposed [e][66-padded n]
    __shared__ float obs_l[D_*HW*20];     // phase B: padded obs tile [d][y][20]
    __shared__ float kl[2304];            // phase B: kern slice (16 channels)
    // phase C arrays
    __shared__ float zin[320];
    __shared__ float z1[HD];
    __shared__ float pla[A_][8];
    __shared__ float pc[32];
    __shared__ float plu[NE][16];
    __shared__ float pld[2][16];
    __shared__ float la[A_];
    __shared__ float lu[NE];
    __shared__ float ld2[2];
    __shared__ float uvals[NE];
    __shared__ float dp[128];
    __shared__ float sc[1];
    __shared__ int   si[4];

    const int q_b = wg >> 6;          // conv quarter
    const int n_b = wg & 63;          // conv n

    for (int t = 0; t < T_; ++t) {
        // ---------- phase A ----------
        if (wg < 144) {
            for (int idx = tid; idx < N_*E_; idx += 256) {
                int n = idx >> 7, e = idx & 127;
                mpT[e*66 + n] = mp_buf[idx];
            }
            __syncthreads();
            int col = wg*64 + (tid & 63);
            int ng  = tid >> 6;
            float acc[16];
            #pragma unroll
            for (int r = 0; r < 16; ++r) acc[r] = 0.f;
            for (int e = 0; e < E_; ++e) {
                float wv = kernel_w[e*KCOLS + col];
                const float* mrow = &mpT[e*66 + ng*16];
                #pragma unroll
                for (int r = 0; r < 16; ++r) acc[r] += mrow[r]*wv;
            }
            float kb = kernel_b[col];
            #pragma unroll
            for (int r = 0; r < 16; ++r)
                kern_buf[(size_t)(ng*16 + r)*KCOLS + col] = acc[r] + kb;
            __syncthreads();
        }
        grid.sync();

        // ---------- phase B (conv, all wgs) ----------
        {
            const float4* op4 = (const float4*)(obs + (size_t)(t*N_ + n_b)*D_*HW*HW);
            #pragma unroll
            for (int k = 0; k < 4; ++k) {
                int idx = tid + k*256;            // 1024 float4s
                int d = idx >> 6, rem = idx & 63;
                int y = rem >> 2, xq = rem & 3;
                *(float4*)&obs_l[d*320 + y*20 + xq*4] = op4[idx];
            }
            const float4* kp4 = (const float4*)(kern_buf + (size_t)n_b*KCOLS + q_b*2304);
            float4* kl4 = (float4*)kl;
            for (int idx = tid; idx < 576; idx += 256) kl4[idx] = kp4[idx];
            __syncthreads();

            int c = tid >> 4, y = tid & 15;
            float acc[16];
            #pragma unroll
            for (int x = 0; x < 16; ++x) acc[x] = 0.f;
            for (int d = 0; d < D_; ++d) {
                const float* kd = &kl[c*144 + d*9];
                #pragma unroll
                for (int ky = 0; ky < 3; ++ky) {
                    int yy = y + ky - 1;
                    if (yy < 0 || yy >= HW) continue;
                    const float4* rs = (const float4*)&obs_l[(d*16 + yy)*20];
                    float4 r0 = rs[0], r1 = rs[1], r2 = rs[2], r3 = rs[3];
                    float row[18];
                    row[0] = 0.f; row[17] = 0.f;
                    row[1]=r0.x; row[2]=r0.y; row[3]=r0.z; row[4]=r0.w;
                    row[5]=r1.x; row[6]=r1.y; row[7]=r1.z; row[8]=r1.w;
                    row[9]=r2.x; row[10]=r2.y; row[11]=r2.z; row[12]=r2.w;
                    row[13]=r3.x; row[14]=r3.y; row[15]=r3.z; row[16]=r3.w;
                    float k0 = kd[ky*3], k1 = kd[ky*3+1], k2 = kd[ky*3+2];
                    #pragma unroll
                    for (int x = 0; x < 16; ++x)
                        acc[x] += row[x]*k0 + row[x+1]*k1 + row[x+2]*k2;
                }
            }
            float bc = conv_bias[q_b*16 + c];
            float psum = 0.f;
            #pragma unroll
            for (int x = 0; x < 16; ++x) psum += fmaxf(acc[x] + bc, 0.f);
            psum += __shfl_xor(psum, 1);
            psum += __shfl_xor(psum, 2);
            psum += __shfl_xor(psum, 4);
            psum += __shfl_xor(psum, 8);
            if (y == 0) h1_buf[n_b*CH + q_b*16 + c] = psum;
            __syncthreads();
        }
        grid.sync();

        // ---------- phase C (heads, wg<64) ----------
        if (wg < 64) {
            int n = wg;
            if (tid < E_)            zin[tid] = mp_buf[n*E_ + tid];
            else if (tid < 192)      zin[tid] = h1_buf[n*CH + (tid - E_)];
            else                     zin[tid] = inv_all[(t*N_ + n)*RH + (tid - 192)];
            if (tid < 64)            zin[256 + tid] = pa_all[(t*N_ + n)*LE + tid];
            if (tid == 0) si[0] = p_cur[n];
            __syncthreads();
            size_t ob = ((size_t)t*N_ + n)*OUTW;
            #pragma unroll
            for (int hh = 0; hh < 2; ++hh) {
                int h = tid + hh*256;
                float acc = zb[h];
                #pragma unroll 4
                for (int i2 = 0; i2 < 320; ++i2) acc += zin[i2]*zw[i2*HD + h];
                float v = fmaxf(acc, 0.f);
                z1[h] = v;
                out[ob + 146 + h] = v;
            }
            __syncthreads();
            // partial sums
            if (tid < 128) {                       // actor: 16 a x 8 parts x 64 MAC
                int a2 = tid >> 3, part = tid & 7;
                float acc = 0.f;
                const float* z0 = z1 + part*64;
                #pragma unroll 8
                for (int h = 0; h < 64; ++h) acc += z0[h]*aw[(part*64 + h)*A_ + a2];
                pla[a2][part] = acc;
            } else if (tid < 160) {                // critic: 32 parts x 16 MAC
                int part = tid - 128;
                float acc = 0.f;
                const float* z0 = z1 + part*16;
                #pragma unroll 8
                for (int h = 0; h < 16; ++h) acc += z0[h]*cw[part*16 + h];
                pc[part] = acc;
            } else if (tid < 224) {                // upsilon: 4 e x 16 parts x 20 MAC
                int r = tid - 160;
                int e = r >> 4, part = r & 15;
                float acc = 0.f;
                #pragma unroll
                for (int k = 0; k < 20; ++k) acc += zin[part*20 + k]*uw[(part*20 + k)*NE + e];
                plu[e][part] = acc;
            } else {                               // dgate: 2 g x 16 parts x 20 MAC
                int r = tid - 224;
                int g = r >> 4, part = r & 15;
                float acc = 0.f;
                #pragma unroll
                for (int k = 0; k < 20; ++k) acc += zin[part*20 + k]*dw[(part*20 + k)*2 + g];
                pld[g][part] = acc;
            }
            __syncthreads();
            if (tid < A_) {
                float acc = ab[tid];
                #pragma unroll
                for (int k = 0; k < 8; ++k) acc += pla[tid][k];
                la[tid] = acc;
            } else if (tid < A_ + NE) {
                int e = tid - A_;
                float acc = ub[e];
                #pragma unroll
                for (int k = 0; k < 16; ++k) acc += plu[e][k];
                lu[e] = acc;
            } else if (tid < A_ + NE + 2) {
                int g = tid - A_ - NE;
                float acc = db[g];
                #pragma unroll
                for (int k = 0; k < 16; ++k) acc += pld[g][k];
                ld2[g] = acc;
            } else if (tid == 24) {
                float acc = cb[0];
                #pragma unroll
                for (int k = 0; k < 32; ++k) acc += pc[k];
                sc[0] = acc;
            }
            __syncthreads();
            if (tid == 0) {
                float mx = la[0];
                #pragma unroll
                for (int k2 = 1; k2 < A_; ++k2) mx = fmaxf(mx, la[k2]);
                float pr[A_]; float sum = 0.f;
                #pragma unroll
                for (int k2 = 0; k2 < A_; ++k2) { pr[k2] = expf(la[k2]-mx); sum += pr[k2]; }
                const float* am = amask + ((size_t)t*N_ + n)*A_;
                float best = -1.f; int bi2 = 0;
                #pragma unroll
                for (int k2 = 0; k2 < A_; ++k2) {
                    float v = pr[k2]/sum * am[k2];
                    out[ob + 1 + k2] = v;
                    if (v > best) { best = v; bi2 = k2; }
                }
                out[ob + 0] = (float)bi2;
            } else if (tid == 1) {
                float mx = fmaxf(fmaxf(lu[0], lu[1]), fmaxf(lu[2], lu[3]));
                float ev[NE]; float s0 = 0.f;
                #pragma unroll
                for (int e = 0; e < NE; ++e) { ev[e] = expf(lu[e]-mx); s0 += ev[e]; }
                #pragma unroll
                for (int e = 0; e < NE; ++e) uvals[e] = ev[e]/s0;
            } else if (tid == 2) {
                float mx = fmaxf(ld2[0], ld2[1]);
                float e0 = expf(ld2[0]-mx), e1 = expf(ld2[1]-mx);
                float s0 = e0 + e1;
                out[ob + 660] = e0/s0;
                out[ob + 661] = e1/s0;
                int dg = (ld2[1] > ld2[0]) ? 1 : 0;
                si[2] = dg;
                out[ob + 662] = (float)dg;
            }
            __syncthreads();
            if (tid < 128) {
                const float* Pp = Pall + ((size_t)(n*NL + si[0])*128 + tid)*NE;
                float v = Pp[0]*uvals[0] + Pp[1]*uvals[1] + Pp[2]*uvals[2] + Pp[3]*uvals[3];
                dp[tid] = v;
                out[ob + 18 + tid] = v;
            }
            __syncthreads();
            if (tid == 0) {
                int dsel;
                if (si[2] == 1) {
                    float best = dp[0]; dsel = 0;
                    for (int j2 = 1; j2 < 128; ++j2) if (dp[j2] > best) { best = dp[j2]; dsel = j2; }
                } else dsel = 64;
                int p = si[0];
                int pn = p + dsel - 64;
                pn = pn < 0 ? 0 : (pn > 63 ? 63 : pn);
                si[3] = pn;
                p_cur[n] = pn;
                out[ob + 17]  = (float)dsel;
                out[ob + 658] = (float)pn;
                out[ob + 659] = sc[0];
            }
            __syncthreads();
            if (tid < E_) {
                mp_buf[n*E_ + tid] = M[(n*NL + si[3])*E_ + tid];
            }
            __syncthreads();
        }
        grid.sync();
    }
}

extern "C" void kernel_launch(void* const* d_in, const int* in_sizes, int n_in,
                              void* d_out, int out_size, void* d_ws, size_t ws_size,
                              hipStream_t stream) {
    (void)in_sizes; (void)n_in; (void)out_size; (void)ws_size;
    const int*   lines    = (const int*)  d_in[0];
    const float* obs      = (const float*)d_in[1];
    const float* invent   = (const float*)d_in[2];
    const int*   pa       = (const int*)  d_in[3];
    const float* amask    = (const float*)d_in[4];
    const int*   p0       = (const int*)  d_in[5];
    const float* emb_task = (const float*)d_in[6];
    const float* emb_low  = (const float*)d_in[7];
    const float* wi_f     = (const float*)d_in[8];
    const float* wh_f     = (const float*)d_in[9];
    const float* bi_f     = (const float*)d_in[10];
    const float* bh_f     = (const float*)d_in[11];
    const float* wi_b     = (const float*)d_in[12];
    const float* wh_b     = (const float*)d_in[13];
    const float* bi_b     = (const float*)d_in[14];
    const float* bh_b     = (const float*)d_in[15];
    const float* beta_w   = (const float*)d_in[16];
    const float* beta_b   = (const float*)d_in[17];
    const float* kernel_w = (const float*)d_in[18];
    const float* kernel_b = (const float*)d_in[19];
    const float* conv_b   = (const float*)d_in[20];
    const float* inv_w    = (const float*)d_in[21];
    const float* inv_b    = (const float*)d_in[22];
    const float* zw       = (const float*)d_in[23];
    const float* zb       = (const float*)d_in[24];
    const float* aw       = (const float*)d_in[25];
    const float* ab       = (const float*)d_in[26];
    const float* uw       = (const float*)d_in[27];
    const float* ub       = (const float*)d_in[28];
    const float* dw       = (const float*)d_in[29];
    const float* db       = (const float*)d_in[30];
    const float* cw       = (const float*)d_in[31];
    const float* cb       = (const float*)d_in[32];
    float* out = (float*)d_out;

    float* ws = (float*)d_ws;
    size_t off = 0;
    float* M        = ws + off; off += (size_t)N_*NL*E_;
    float* wiT4     = ws + off; off += 2*32*384*4;
    float* whT4     = ws + off; off += 2*32*384*4;
    float* giM      = ws + off; off += (size_t)2*N_*NL*G3;
    float* Ball     = ws + off; off += (size_t)N_*NL*128*NE;
    float* Pall     = ws + off; off += (size_t)N_*NL*128*NE;
    float* inv_all  = ws + off; off += (size_t)T_*N_*RH;
    float* pa_all   = ws + off; off += (size_t)T_*N_*LE;
    float* kern_buf = ws + off; off += (size_t)N_*KCOLS;
    float* h1_buf   = ws + off; off += (size_t)N_*CH;
    float* mp_buf   = ws + off; off += (size_t)N_*E_;
    int*   p_cur    = (int*)(ws + off); off += 64;

    k_prep_M<<<N_*NL, 128, 0, stream>>>(lines, emb_task, M);
    k_prep_T4<<<768, 128, 0, stream>>>(wi_f, wi_b, wh_f, wh_b, wiT4, whT4);
    k_prep_misc<<<N_, 128, 0, stream>>>(p0, M, p_cur, mp_buf);
    k_prep_invpa<<<T_*N_, 64, 0, stream>>>(invent, inv_w, inv_b, pa, emb_low, inv_all, pa_all);
    k_giM<<<dim3(8, N_, 2), 384, 0, stream>>>(M, wiT4, bi_f, bi_b, giM);
    k_gru<<<dim3(4, N_, 2), 256, 0, stream>>>(giM, whT4, bh_f, bh_b, beta_w, beta_b, Ball);
    k_P<<<N_*NL, 64, 0, stream>>>(Ball, Pall);

    void* args[] = {
        (void*)&obs, (void*)&kernel_w, (void*)&kernel_b, (void*)&conv_b,
        (void*)&amask, (void*)&Pall, (void*)&M,
        (void*)&inv_all, (void*)&pa_all,
        (void*)&zw, (void*)&zb, (void*)&aw, (void*)&ab,
        (void*)&uw, (void*)&ub, (void*)&dw, (void*)&db,
        (void*)&cw, (void*)&cb,
        (void*)&kern_buf, (void*)&h1_buf, (void*)&mp_buf, (void*)&p_cur, (void*)&out
    };
    hipLaunchCooperativeKernel((const void*)k_loop, dim3(256), dim3(256), args, 0, stream);
}

// Round 4
// 2904.747 us; speedup vs baseline: 2.2220x; 2.2220x over previous
//
#include <hip/hip_runtime.h>
#include <math.h>

#define T_   32
#define N_   64
#define NL   64
#define E_   128
#define G3   384   // 3*E
#define NE   4
#define CH   64
#define D_   16
#define HW   16
#define RH   64
#define LE   64
#define HD   512
#define A_   16
#define INVN 32
#define KCOLS 9216 // CH*D_*3*3
#define OUTW 663

__device__ __forceinline__ float sigf(float x) { return 1.f/(1.f+expf(-x)); }

// ---------------- prep kernels ----------------

__global__ __launch_bounds__(128) void k_prep_M(const int* lines, const float* emb_task, float* M) {
    int nl = blockIdx.x;
    int i  = threadIdx.x;
    const int* ln = lines + nl*4;
    float s = 0.f;
    #pragma unroll
    for (int t = 0; t < 4; ++t) s += emb_task[ln[t]*E_ + i];
    M[nl*E_ + i] = s;
}

// T4[((dir*32 + k/4)*384 + g)*4 + (k%4)] = w[dir][g*128+k]
__global__ __launch_bounds__(128) void k_prep_T4(const float* wif, const float* wib,
                                                 const float* whf, const float* whb,
                                                 float* wiT4, float* whT4) {
    int g = blockIdx.x % 384, dir = blockIdx.x / 384;
    int k = threadIdx.x;
    const float* wi = dir ? wib : wif;
    const float* wh = dir ? whb : whf;
    int dst = ((dir*32 + (k>>2))*384 + g)*4 + (k&3);
    wiT4[dst] = wi[g*128 + k];
    whT4[dst] = wh[g*128 + k];
}

__global__ __launch_bounds__(128) void k_prep_misc(const int* p0, const float* M, int* p_cur, float* mp) {
    int n = blockIdx.x, i = threadIdx.x;
    int p = p0[n];
    if (i == 0) p_cur[n] = p;
    mp[n*E_ + i] = M[(n*NL + p)*E_ + i];
}

__global__ __launch_bounds__(64) void k_prep_invpa(const float* inv, const float* inv_w, const float* inv_b,
                                                   const int* pa, const float* emb_lower,
                                                   float* inv_all, float* pa_all) {
    int tn = blockIdx.x, r = threadIdx.x;
    const float* iv = inv + tn*INVN;
    float acc = inv_b[r];
    #pragma unroll
    for (int i = 0; i < INVN; ++i) acc += iv[i]*inv_w[i*RH + r];
    inv_all[tn*RH + r] = fmaxf(acc, 0.f);
    const int* pp = pa + tn*4;
    float s = 0.f;
    #pragma unroll
    for (int j = 0; j < 4; ++j) s += emb_lower[pp[j]*LE + r];
    pa_all[tn*LE + r] = s;
}

// giM[dir][n][l][g] = M[n][l] . wi[g] + bi[g]
__global__ __launch_bounds__(384) void k_giM(const float* M, const float* wiT4,
                                             const float* bif, const float* bib, float* giM) {
    int lblk = blockIdx.x, n = blockIdx.y, dir = blockIdx.z;
    int g = threadIdx.x;
    __shared__ float Ml[8][E_];
    for (int idx = g; idx < 8*E_; idx += 384) {
        int r = idx >> 7, k = idx & 127;
        Ml[r][k] = M[(n*NL + lblk*8 + r)*E_ + k];
    }
    __syncthreads();
    float acc[8];
    #pragma unroll
    for (int r = 0; r < 8; ++r) acc[r] = 0.f;
    const float4* W = (const float4*)(wiT4) + dir*32*384;
    for (int kq = 0; kq < 32; ++kq) {
        float4 w = W[kq*384 + g];
        #pragma unroll
        for (int r = 0; r < 8; ++r) {
            float4 h = *(const float4*)&Ml[r][kq*4];
            acc[r] += w.x*h.x + w.y*h.y + w.z*h.z + w.w*h.w;
        }
    }
    float bi = dir ? bib[g] : bif[g];
    #pragma unroll
    for (int r = 0; r < 8; ++r)
        giM[((dir*N_ + n)*NL + lblk*8 + r)*G3 + g] = acc[r] + bi;
}

// GRU over all rolls. grid (pblk 4, n 64, dir 2) = 512 wgs, 256 thr.
__global__ __launch_bounds__(256) void k_gru(const float* giM, const float* whT4,
                                             const float* bhf, const float* bhb,
                                             const float* beta_w, const float* beta_b,
                                             float* Ball) {
    int pblk = blockIdx.x, n = blockIdx.y, dir = blockIdx.z;
    int tid = threadIdx.x;
    int i = tid & 127;
    int sb = tid >> 7;

    __shared__ float Hs[16][132];
    __shared__ float bwT[NE][132];
    for (int idx = tid; idx < 16*132; idx += 256) ((float*)Hs)[idx] = 0.f;
    for (int idx = tid; idx < E_*NE; idx += 256) {
        int k = idx >> 2, e = idx & 3;
        bwT[e][k] = beta_w[k*NE + e];
    }
    const float* bh = dir ? bhb : bhf;
    float bhr = bh[i], bhz = bh[128+i], bhn = bh[256+i];
    const float4* W = (const float4*)(whT4) + dir*32*384;
    const float* giBase = giM + (dir*N_ + n)*NL*G3;
    int bs = tid >> 4;          // seq 0..15
    int bpart = (tid >> 2) & 3; // k-part (strided)
    int be = tid & 3;           // expert
    float bbias = beta_b[be];
    __syncthreads();

    for (int j = 0; j < NL; ++j) {
        float accr[8], accz[8], accn[8];
        #pragma unroll
        for (int s = 0; s < 8; ++s) { accr[s]=bhr; accz[s]=bhz; accn[s]=bhn; }
        #pragma unroll 2
        for (int kq = 0; kq < 32; ++kq) {
            float4 wr = W[kq*384 + i];
            float4 wz = W[kq*384 + 128 + i];
            float4 wn = W[kq*384 + 256 + i];
            #pragma unroll
            for (int s = 0; s < 8; ++s) {
                float4 h = *(const float4*)&Hs[sb*8 + s][kq*4];
                accr[s] += wr.x*h.x + wr.y*h.y + wr.z*h.z + wr.w*h.w;
                accz[s] += wz.x*h.x + wz.y*h.y + wz.z*h.z + wz.w*h.w;
                accn[s] += wn.x*h.x + wn.y*h.y + wn.z*h.z + wn.w*h.w;
            }
        }
        float hnew[8];
        #pragma unroll
        for (int s = 0; s < 8; ++s) {
            int ss = sb*8 + s;
            int p  = pblk*16 + ss;
            int l  = dir ? ((p + 63 - j) & 63) : ((p + j) & 63);
            const float* gi = giBase + l*G3;
            float r  = sigf(gi[i]       + accr[s]);
            float z  = sigf(gi[128+i]   + accz[s]);
            float nn = tanhf(gi[256+i]  + r*accn[s]);
            hnew[s] = (1.f - z)*nn + z*Hs[ss][i];
        }
        __syncthreads();
        #pragma unroll
        for (int s = 0; s < 8; ++s) Hs[sb*8 + s][i] = hnew[s];
        __syncthreads();
        // beta head: strided k split -> conflict-free (bpart*1 stride, not *32)
        {
            float acc = 0.f;
            const float* hrow = &Hs[bs][0];
            const float* brow = &bwT[be][0];
            #pragma unroll 8
            for (int k = 0; k < 32; ++k) {
                int k2 = bpart + 4*k;
                acc += hrow[k2]*brow[k2];
            }
            acc += __shfl_xor(acc, 4);
            acc += __shfl_xor(acc, 8);
            if (bpart == 0) {
                float bval = sigf(acc + bbias);
                int p = pblk*16 + bs;
                int j2 = 2*j + dir;
                Ball[((n*NL + p)*128 + j2)*NE + be] = bval;
            }
        }
    }
}

// stick-breaking -> reordered P_final[n][p][j][e]
__global__ __launch_bounds__(64) void k_P(const float* Ball, float* Pall) {
    int np = blockIdx.x;
    int tid = threadIdx.x;
    __shared__ float B[128][NE];
    __shared__ float Pf[128][NE];
    const float* src = Ball + np*128*NE;
    for (int idx = tid; idx < 128*NE; idx += 64) ((float*)B)[idx] = src[idx];
    __syncthreads();
    if (tid < NE) {
        int e = tid;
        float c = 1.f;
        for (int j2 = 0; j2 < 128; ++j2) {
            float bz = (j2 == 0 || j2 == 127) ? 0.f : B[j2][e];
            float bf = (j2 == 127) ? 1.f : bz;
            Pf[j2][e] = bf * c;
            c *= (1.f - bz);
        }
    }
    __syncthreads();
    float* dst = Pall + np*128*NE;
    for (int idx = tid; idx < 128*NE; idx += 64) {
        int j = idx >> 2, e = idx & 3;
        int jf = (j < 64) ? (2*(63 - j) + 1) : (2*(j - 64));
        dst[idx] = Pf[jf][e];
    }
}

// ---------------- head-GEMM precomputes ----------------
// zmp[row][h] = M[row,:] @ zw[0:128, h]   (row = n*64+p, 4096 rows)
__global__ __launch_bounds__(256) void k_zmp(const float* M, const float* zw, float* zmp) {
    int cb = blockIdx.x, rb = blockIdx.y;   // cb<2 (256 cols), rb<128 (32 rows)
    int tid = threadIdx.x;
    __shared__ float At[32][E_];
    for (int idx = tid; idx < 32*E_; idx += 256) {
        int r = idx >> 7, k = idx & 127;
        At[r][k] = M[(rb*32 + r)*E_ + k];
    }
    __syncthreads();
    float acc[32];
    #pragma unroll
    for (int r = 0; r < 32; ++r) acc[r] = 0.f;
    int col = cb*256 + tid;
    #pragma unroll 4
    for (int k = 0; k < E_; ++k) {
        float w = zw[k*HD + col];
        #pragma unroll
        for (int r = 0; r < 32; ++r) acc[r] += At[r][k]*w;
    }
    #pragma unroll
    for (int r = 0; r < 32; ++r)
        zmp[(size_t)(rb*32 + r)*HD + col] = acc[r];
}

// zip[row][h] = [inv|pa][row,:] @ zw[192:320, h] + zb[h]   (row = t*64+n, 2048 rows)
__global__ __launch_bounds__(256) void k_ip(const float* inv_all, const float* pa_all,
                                            const float* zw, const float* zb, float* zip) {
    int cb = blockIdx.x, rb = blockIdx.y;   // cb<2, rb<64
    int tid = threadIdx.x;
    __shared__ float At[32][E_];
    for (int idx = tid; idx < 32*E_; idx += 256) {
        int r = idx >> 7, k = idx & 127;
        int row = rb*32 + r;
        At[r][k] = (k < 64) ? inv_all[row*RH + k] : pa_all[row*LE + (k - 64)];
    }
    __syncthreads();
    float acc[32];
    #pragma unroll
    for (int r = 0; r < 32; ++r) acc[r] = 0.f;
    int col = cb*256 + tid;
    #pragma unroll 4
    for (int k = 0; k < E_; ++k) {
        float w = zw[(192 + k)*HD + col];
        #pragma unroll
        for (int r = 0; r < 32; ++r) acc[r] += At[r][k]*w;
    }
    float b = zb[col];
    #pragma unroll
    for (int r = 0; r < 32; ++r)
        zip[(size_t)(rb*32 + r)*HD + col] = acc[r] + b;
}

// ump[row][e] (4), dmp[row][g] (2) from M rows
__global__ __launch_bounds__(256) void k_mpsmall(const float* M, const float* uw, const float* dw,
                                                 float* ump, float* dmp) {
    int wg = blockIdx.x;   // 64 wgs x 64 rows
    int tid = threadIdx.x;
    __shared__ float Mt[64][E_];
    for (int idx = tid; idx < 64*E_; idx += 256)
        ((float*)Mt)[idx] = M[(size_t)wg*64*E_ + idx];
    __syncthreads();
    int r = tid >> 2, q = tid & 3;
    float au = 0.f, ad = 0.f;
    #pragma unroll 4
    for (int k = 0; k < E_; ++k) {
        float m = Mt[r][k];
        au += m*uw[k*NE + q];
        if (q < 2) ad += m*dw[k*2 + q];
    }
    int row = wg*64 + r;
    ump[row*NE + q] = au;
    if (q < 2) dmp[row*2 + q] = ad;
}

// uip[row][e] (+ub), dip[row][g] (+db) from inv/pa rows
__global__ __launch_bounds__(256) void k_ipsmall(const float* inv_all, const float* pa_all,
                                                 const float* uw, const float* ub,
                                                 const float* dw, const float* db,
                                                 float* uip, float* dip) {
    int wg = blockIdx.x;   // 32 wgs x 64 rows
    int tid = threadIdx.x;
    __shared__ float At[64][E_];
    for (int idx = tid; idx < 64*E_; idx += 256) {
        int r = idx >> 7, k = idx & 127;
        int row = wg*64 + r;
        At[r][k] = (k < 64) ? inv_all[row*RH + k] : pa_all[row*LE + (k - 64)];
    }
    __syncthreads();
    int r = tid >> 2, q = tid & 3;
    float au = ub[q], ad = (q < 2) ? db[q] : 0.f;
    #pragma unroll 4
    for (int k = 0; k < E_; ++k) {
        float v = At[r][k];
        au += v*uw[(192 + k)*NE + q];
        if (q < 2) ad += v*dw[(192 + k)*2 + q];
    }
    int row = wg*64 + r;
    uip[row*NE + q] = au;
    if (q < 2) dip[row*2 + q] = ad;
}

// ---------------- per-step kernels ----------------

// kern_buf[n][col] = mp[n] . kernel_w[:,col] + kernel_b[col]; grid 288 x 256
__global__ __launch_bounds__(256) void k_kern(const float* mp, const float* kernel_w,
                                              const float* kernel_b, float* kern_buf) {
    int tid = threadIdx.x;
    int col = blockIdx.x*32 + (tid & 31);
    int rg  = tid >> 5;      // 8 groups of 8 n
    __shared__ float ml[E_][68];
    for (int idx = tid; idx < N_*E_; idx += 256) {
        int nn2 = idx >> 7, e = idx & 127;
        ml[e][nn2] = mp[idx];
    }
    __syncthreads();
    float acc[8];
    #pragma unroll
    for (int r = 0; r < 8; ++r) acc[r] = 0.f;
    #pragma unroll 8
    for (int e = 0; e < E_; ++e) {
        float w = kernel_w[e*KCOLS + col];
        const float* mrow = &ml[e][rg*8];
        #pragma unroll
        for (int r = 0; r < 8; ++r) acc[r] += mrow[r]*w;
    }
    float kb = kernel_b[col];
    #pragma unroll
    for (int r = 0; r < 8; ++r)
        kern_buf[(size_t)(rg*8 + r)*KCOLS + col] = acc[r] + kb;
}

// conv: grid (q 4, n 64) x 256 thr -> h1_buf[n][c]
__global__ __launch_bounds__(256) void k_conv(const float* obs, const float* kern_buf,
                                              const float* conv_bias, float* h1_buf, int t) {
    int q_b = blockIdx.x, n_b = blockIdx.y;
    int tid = threadIdx.x;
    __shared__ float obs_l[D_*HW*20];
    __shared__ float kl[2304];
    const float4* op4 = (const float4*)(obs + (size_t)(t*N_ + n_b)*D_*HW*HW);
    #pragma unroll
    for (int k = 0; k < 4; ++k) {
        int idx = tid + k*256;
        int d = idx >> 6, rem = idx & 63;
        int y = rem >> 2, xq = rem & 3;
        *(float4*)&obs_l[d*320 + y*20 + xq*4] = op4[idx];
    }
    const float4* kp4 = (const float4*)(kern_buf + (size_t)n_b*KCOLS + q_b*2304);
    float4* kl4 = (float4*)kl;
    for (int idx = tid; idx < 576; idx += 256) kl4[idx] = kp4[idx];
    __syncthreads();

    int c = tid >> 4, y = tid & 15;
    float acc[16];
    #pragma unroll
    for (int x = 0; x < 16; ++x) acc[x] = 0.f;
    for (int d = 0; d < D_; ++d) {
        const float* kd = &kl[c*144 + d*9];
        #pragma unroll
        for (int ky = 0; ky < 3; ++ky) {
            int yy = y + ky - 1;
            if (yy < 0 || yy >= HW) continue;
            const float4* rs = (const float4*)&obs_l[(d*16 + yy)*20];
            float4 r0 = rs[0], r1 = rs[1], r2 = rs[2], r3 = rs[3];
            float row[18];
            row[0] = 0.f; row[17] = 0.f;
            row[1]=r0.x; row[2]=r0.y; row[3]=r0.z; row[4]=r0.w;
            row[5]=r1.x; row[6]=r1.y; row[7]=r1.z; row[8]=r1.w;
            row[9]=r2.x; row[10]=r2.y; row[11]=r2.z; row[12]=r2.w;
            row[13]=r3.x; row[14]=r3.y; row[15]=r3.z; row[16]=r3.w;
            float k0 = kd[ky*3], k1 = kd[ky*3+1], k2 = kd[ky*3+2];
            #pragma unroll
            for (int x = 0; x < 16; ++x)
                acc[x] += row[x]*k0 + row[x+1]*k1 + row[x+2]*k2;
        }
    }
    float bc = conv_bias[q_b*16 + c];
    float psum = 0.f;
    #pragma unroll
    for (int x = 0; x < 16; ++x) psum += fmaxf(acc[x] + bc, 0.f);
    psum += __shfl_xor(psum, 1);
    psum += __shfl_xor(psum, 2);
    psum += __shfl_xor(psum, 4);
    psum += __shfl_xor(psum, 8);
    if (y == 0) h1_buf[n_b*CH + q_b*16 + c] = psum;
}

// heads: grid 64 (n) x 256 thr
__global__ __launch_bounds__(256) void k_heads(
    const float* h1_buf, const float* zmp, const float* zip,
    const float* ump, const float* uip, const float* dmp, const float* dip,
    const float* zw, const float* aw, const float* ab,
    const float* uw, const float* dw, const float* cw, const float* cb,
    const float* amask, const float* Pall, const float* M,
    float* mp_buf, int* p_cur, float* out, int t) {
    int n = blockIdx.x, tid = threadIdx.x;
    __shared__ float h1s[CH];
    __shared__ float z1s[HD];
    __shared__ float pla[A_][8];
    __shared__ float pc[32];
    __shared__ float la[A_];
    __shared__ float lu[NE];
    __shared__ float ld2[2];
    __shared__ float uvals[NE];
    __shared__ float dp[128];
    __shared__ float sc[1];
    __shared__ int   si[4];

    if (tid < CH) h1s[tid] = h1_buf[n*CH + tid];
    if (tid == 0) si[0] = p_cur[n];
    __syncthreads();
    int p = si[0];
    size_t ob = ((size_t)t*N_ + n)*OUTW;

    // z1: 2 h per thread, K=64 (h1 part only; m/inv/pa parts precomputed)
    const float* zmpp = zmp + (size_t)(n*NL + p)*HD;
    const float* zipp = zip + (size_t)(t*N_ + n)*HD;
    #pragma unroll
    for (int hh = 0; hh < 2; ++hh) {
        int h = tid + hh*256;
        float acc = zmpp[h] + zipp[h];
        #pragma unroll 8
        for (int c = 0; c < CH; ++c) acc += h1s[c]*zw[(E_ + c)*HD + h];
        float v = fmaxf(acc, 0.f);
        z1s[h] = v;
        out[ob + 146 + h] = v;
    }
    __syncthreads();

    // head partials
    if (tid < 128) {                       // actor: 16 a x 8 parts x 64 MAC
        int a2 = tid >> 3, part = tid & 7;
        float acc = 0.f;
        const float* z0 = z1s + part*64;
        #pragma unroll 8
        for (int h = 0; h < 64; ++h) acc += z0[h]*aw[(part*64 + h)*A_ + a2];
        pla[a2][part] = acc;
    } else if (tid < 160) {                // critic: 32 parts x 16 MAC
        int part = tid - 128;
        float acc = 0.f;
        const float* z0 = z1s + part*16;
        #pragma unroll 8
        for (int h = 0; h < 16; ++h) acc += z0[h]*cw[part*16 + h];
        pc[part] = acc;
    } else if (tid < 164) {                // upsilon (K=64 h1 part + precomputed)
        int e = tid - 160;
        float acc = ump[(n*NL + p)*NE + e] + uip[(t*N_ + n)*NE + e];
        #pragma unroll 8
        for (int c = 0; c < CH; ++c) acc += h1s[c]*uw[(E_ + c)*NE + e];
        lu[e] = acc;
    } else if (tid < 166) {                // dgate
        int g = tid - 164;
        float acc = dmp[(n*NL + p)*2 + g] + dip[(t*N_ + n)*2 + g];
        #pragma unroll 8
        for (int c = 0; c < CH; ++c) acc += h1s[c]*dw[(E_ + c)*2 + g];
        ld2[g] = acc;
    }
    __syncthreads();
    if (tid < A_) {
        float acc = ab[tid];
        #pragma unroll
        for (int k = 0; k < 8; ++k) acc += pla[tid][k];
        la[tid] = acc;
    } else if (tid == 24) {
        float acc = cb[0];
        #pragma unroll
        for (int k = 0; k < 32; ++k) acc += pc[k];
        sc[0] = acc;
    }
    __syncthreads();

    if (tid == 0) {
        float mx = la[0];
        #pragma unroll
        for (int k2 = 1; k2 < A_; ++k2) mx = fmaxf(mx, la[k2]);
        float pr[A_]; float sum = 0.f;
        #pragma unroll
        for (int k2 = 0; k2 < A_; ++k2) { pr[k2] = expf(la[k2]-mx); sum += pr[k2]; }
        const float* am = amask + ((size_t)t*N_ + n)*A_;
        float best = -1.f; int bi2 = 0;
        #pragma unroll
        for (int k2 = 0; k2 < A_; ++k2) {
            float v = pr[k2]/sum * am[k2];
            out[ob + 1 + k2] = v;
            if (v > best) { best = v; bi2 = k2; }
        }
        out[ob + 0] = (float)bi2;
    } else if (tid == 1) {
        float mx = fmaxf(fmaxf(lu[0], lu[1]), fmaxf(lu[2], lu[3]));
        float ev[NE]; float s0 = 0.f;
        #pragma unroll
        for (int e = 0; e < NE; ++e) { ev[e] = expf(lu[e]-mx); s0 += ev[e]; }
        #pragma unroll
        for (int e = 0; e < NE; ++e) uvals[e] = ev[e]/s0;
    } else if (tid == 2) {
        float mx = fmaxf(ld2[0], ld2[1]);
        float e0 = expf(ld2[0]-mx), e1 = expf(ld2[1]-mx);
        float s0 = e0 + e1;
        out[ob + 660] = e0/s0;
        out[ob + 661] = e1/s0;
        int dg = (ld2[1] > ld2[0]) ? 1 : 0;
        si[2] = dg;
        out[ob + 662] = (float)dg;
    }
    __syncthreads();
    if (tid < 128) {
        const float* Pp = Pall + ((size_t)(n*NL + p)*128 + tid)*NE;
        float v = Pp[0]*uvals[0] + Pp[1]*uvals[1] + Pp[2]*uvals[2] + Pp[3]*uvals[3];
        dp[tid] = v;
        out[ob + 18 + tid] = v;
    }
    __syncthreads();
    if (tid == 0) {
        int dsel;
        if (si[2] == 1) {
            float best = dp[0]; dsel = 0;
            for (int j2 = 1; j2 < 128; ++j2) if (dp[j2] > best) { best = dp[j2]; dsel = j2; }
        } else dsel = 64;
        int pn = p + dsel - 64;
        pn = pn < 0 ? 0 : (pn > 63 ? 63 : pn);
        si[3] = pn;
        p_cur[n] = pn;
        out[ob + 17]  = (float)dsel;
        out[ob + 658] = (float)pn;
        out[ob + 659] = sc[0];
    }
    __syncthreads();
    if (tid < E_) {
        mp_buf[n*E_ + tid] = M[(n*NL + si[3])*E_ + tid];
    }
}

extern "C" void kernel_launch(void* const* d_in, const int* in_sizes, int n_in,
                              void* d_out, int out_size, void* d_ws, size_t ws_size,
                              hipStream_t stream) {
    (void)in_sizes; (void)n_in; (void)out_size; (void)ws_size;
    const int*   lines    = (const int*)  d_in[0];
    const float* obs      = (const float*)d_in[1];
    const float* invent   = (const float*)d_in[2];
    const int*   pa       = (const int*)  d_in[3];
    const float* amask    = (const float*)d_in[4];
    const int*   p0       = (const int*)  d_in[5];
    const float* emb_task = (const float*)d_in[6];
    const float* emb_low  = (const float*)d_in[7];
    const float* wi_f     = (const float*)d_in[8];
    const float* wh_f     = (const float*)d_in[9];
    const float* bi_f     = (const float*)d_in[10];
    const float* bh_f     = (const float*)d_in[11];
    const float* wi_b     = (const float*)d_in[12];
    const float* wh_b     = (const float*)d_in[13];
    const float* bi_b     = (const float*)d_in[14];
    const float* bh_b     = (const float*)d_in[15];
    const float* beta_w   = (const float*)d_in[16];
    const float* beta_b   = (const float*)d_in[17];
    const float* kernel_w = (const float*)d_in[18];
    const float* kernel_b = (const float*)d_in[19];
    const float* conv_b   = (const float*)d_in[20];
    const float* inv_w    = (const float*)d_in[21];
    const float* inv_b    = (const float*)d_in[22];
    const float* zw       = (const float*)d_in[23];
    const float* zb       = (const float*)d_in[24];
    const float* aw       = (const float*)d_in[25];
    const float* ab       = (const float*)d_in[26];
    const float* uw       = (const float*)d_in[27];
    const float* ub       = (const float*)d_in[28];
    const float* dw       = (const float*)d_in[29];
    const float* db       = (const float*)d_in[30];
    const float* cw       = (const float*)d_in[31];
    const float* cb       = (const float*)d_in[32];
    float* out = (float*)d_out;

    float* ws = (float*)d_ws;
    size_t off = 0;
    float* M        = ws + off; off += (size_t)N_*NL*E_;
    float* wiT4     = ws + off; off += 2*32*384*4;
    float* whT4     = ws + off; off += 2*32*384*4;
    float* giM      = ws + off; off += (size_t)2*N_*NL*G3;
    float* Ball     = ws + off; off += (size_t)N_*NL*128*NE;
    float* Pall     = ws + off; off += (size_t)N_*NL*128*NE;
    float* inv_all  = ws + off; off += (size_t)T_*N_*RH;
    float* pa_all   = ws + off; off += (size_t)T_*N_*LE;
    float* kern_buf = ws + off; off += (size_t)N_*KCOLS;
    float* h1_buf   = ws + off; off += (size_t)N_*CH;
    float* mp_buf   = ws + off; off += (size_t)N_*E_;
    float* zmp      = ws + off; off += (size_t)N_*NL*HD;     // 8 MB
    float* zip      = ws + off; off += (size_t)T_*N_*HD;     // 4 MB
    float* ump      = ws + off; off += (size_t)N_*NL*NE;
    float* dmp      = ws + off; off += (size_t)N_*NL*2;
    float* uip      = ws + off; off += (size_t)T_*N_*NE;
    float* dip      = ws + off; off += (size_t)T_*N_*2;
    int*   p_cur    = (int*)(ws + off); off += 64;

    k_prep_M<<<N_*NL, 128, 0, stream>>>(lines, emb_task, M);
    k_prep_T4<<<768, 128, 0, stream>>>(wi_f, wi_b, wh_f, wh_b, wiT4, whT4);
    k_prep_misc<<<N_, 128, 0, stream>>>(p0, M, p_cur, mp_buf);
    k_prep_invpa<<<T_*N_, 64, 0, stream>>>(invent, inv_w, inv_b, pa, emb_low, inv_all, pa_all);
    k_giM<<<dim3(8, N_, 2), 384, 0, stream>>>(M, wiT4, bi_f, bi_b, giM);
    k_gru<<<dim3(4, N_, 2), 256, 0, stream>>>(giM, whT4, bh_f, bh_b, beta_w, beta_b, Ball);
    k_P<<<N_*NL, 64, 0, stream>>>(Ball, Pall);
    k_zmp<<<dim3(2, 128), 256, 0, stream>>>(M, zw, zmp);
    k_ip<<<dim3(2, 64), 256, 0, stream>>>(inv_all, pa_all, zw, zb, zip);
    k_mpsmall<<<64, 256, 0, stream>>>(M, uw, dw, ump, dmp);
    k_ipsmall<<<32, 256, 0, stream>>>(inv_all, pa_all, uw, ub, dw, db, uip, dip);

    for (int t = 0; t < T_; ++t) {
        k_kern<<<KCOLS/32, 256, 0, stream>>>(mp_buf, kernel_w, kernel_b, kern_buf);
        k_conv<<<dim3(4, N_), 256, 0, stream>>>(obs, kern_buf, conv_b, h1_buf, t);
        k_heads<<<N_, 256, 0, stream>>>(h1_buf, zmp, zip, ump, uip, dmp, dip,
                                        zw, aw, ab, uw, dw, cw, cb,
                                        amask, Pall, M, mp_buf, p_cur, out, t);
    }
}

// Round 5
// 1926.661 us; speedup vs baseline: 3.3499x; 1.5077x over previous
//
#include <hip/hip_runtime.h>
#include <math.h>

#define T_   32
#define N_   64
#define NL   64
#define E_   128
#define G3   384   // 3*E
#define NE   4
#define CH   64
#define D_   16
#define HW   16
#define RH   64
#define LE   64
#define HD   512
#define A_   16
#define INVN 32
#define KCOLS 9216 // CH*D_*3*3
#define OUTW 663

typedef _Float16 half8 __attribute__((ext_vector_type(8)));
typedef float floatx4 __attribute__((ext_vector_type(4)));

__device__ __forceinline__ float sigf(float x) { return 1.f/(1.f+expf(-x)); }

// ---------------- prep kernels ----------------

__global__ __launch_bounds__(128) void k_prep_M(const int* lines, const float* emb_task, float* M) {
    int nl = blockIdx.x;
    int i  = threadIdx.x;
    const int* ln = lines + nl*4;
    float s = 0.f;
    #pragma unroll
    for (int t = 0; t < 4; ++t) s += emb_task[ln[t]*E_ + i];
    M[nl*E_ + i] = s;
}

// wiT4[((dir*32 + k/4)*384 + g)*4 + (k%4)] = wi[dir][g*128+k]
__global__ __launch_bounds__(128) void k_prep_T4(const float* wif, const float* wib, float* wiT4) {
    int g = blockIdx.x % 384, dir = blockIdx.x / 384;
    int k = threadIdx.x;
    const float* wi = dir ? wib : wif;
    int dst = ((dir*32 + (k>>2))*384 + g)*4 + (k&3);
    wiT4[dst] = wi[g*128 + k];
}

// pack Wh into per-wave fp16 hi/lo B-fragments.
// frag idx f = (((dir*4 + w)*4 + kt)*2 + term)*6 + nt ; elem = lane*8 + e
// element = W_term[k = kt*32 + (lane>>4)*8 + e][g = gt*128 + w*32 + isub*16 + (lane&15)]
__global__ __launch_bounds__(64) void k_packW(const float* whf, const float* whb, _Float16* WBpack) {
    int f = blockIdx.x;        // 0..383
    int lane = threadIdx.x;
    int nt = f % 6; int rest = f / 6;
    int term = rest % 2; rest /= 2;
    int kt = rest % 4; rest /= 4;
    int w = rest % 4; int dir = rest / 4;
    const float* wh = dir ? whb : whf;
    int gt = nt >> 1, isub = nt & 1;
    int g  = gt*128 + w*32 + isub*16 + (lane & 15);
    int k0 = kt*32 + (lane >> 4)*8;
    _Float16* dst = WBpack + (size_t)f*512 + lane*8;
    #pragma unroll
    for (int e = 0; e < 8; ++e) {
        float v = wh[g*128 + k0 + e];
        _Float16 hi = (_Float16)v;
        dst[e] = (term == 0) ? hi : (_Float16)(v - (float)hi);
    }
}

__global__ __launch_bounds__(128) void k_prep_misc(const int* p0, const float* M, int* p_cur, float* mp) {
    int n = blockIdx.x, i = threadIdx.x;
    int p = p0[n];
    if (i == 0) p_cur[n] = p;
    mp[n*E_ + i] = M[(n*NL + p)*E_ + i];
}

__global__ __launch_bounds__(64) void k_prep_invpa(const float* inv, const float* inv_w, const float* inv_b,
                                                   const int* pa, const float* emb_lower,
                                                   float* inv_all, float* pa_all) {
    int tn = blockIdx.x, r = threadIdx.x;
    const float* iv = inv + tn*INVN;
    float acc = inv_b[r];
    #pragma unroll
    for (int i = 0; i < INVN; ++i) acc += iv[i]*inv_w[i*RH + r];
    inv_all[tn*RH + r] = fmaxf(acc, 0.f);
    const int* pp = pa + tn*4;
    float s = 0.f;
    #pragma unroll
    for (int j = 0; j < 4; ++j) s += emb_lower[pp[j]*LE + r];
    pa_all[tn*LE + r] = s;
}

// giM[dir][n][l][g] = M[n][l] . wi[g] + bi[g]
__global__ __launch_bounds__(384) void k_giM(const float* M, const float* wiT4,
                                             const float* bif, const float* bib, float* giM) {
    int lblk = blockIdx.x, n = blockIdx.y, dir = blockIdx.z;
    int g = threadIdx.x;
    __shared__ float Ml[8][E_];
    for (int idx = g; idx < 8*E_; idx += 384) {
        int r = idx >> 7, k = idx & 127;
        Ml[r][k] = M[(n*NL + lblk*8 + r)*E_ + k];
    }
    __syncthreads();
    float acc[8];
    #pragma unroll
    for (int r = 0; r < 8; ++r) acc[r] = 0.f;
    const float4* W = (const float4*)(wiT4) + dir*32*384;
    for (int kq = 0; kq < 32; ++kq) {
        float4 w = W[kq*384 + g];
        #pragma unroll
        for (int r = 0; r < 8; ++r) {
            float4 h = *(const float4*)&Ml[r][kq*4];
            acc[r] += w.x*h.x + w.y*h.y + w.z*h.z + w.w*h.w;
        }
    }
    float bi = dir ? bib[g] : bif[g];
    #pragma unroll
    for (int r = 0; r < 8; ++r)
        giM[((dir*N_ + n)*NL + lblk*8 + r)*G3 + g] = acc[r] + bi;
}

// ---------------- MFMA GRU ----------------
// grid (half 2, n 64, dir 2) = 256 wgs x 256 thr. wg handles 32 seqs (p = half*32+seq).
// Wave w owns i-range [32w, 32w+32) of all 3 gate types; W resident in VGPRs (fp16 hi/lo).
// Per j: C-init from giM(+bh), 144 MFMAs, fp32 epilogue, h round-trip via LDS, beta head.
__global__ __launch_bounds__(256, 1) void k_gru(const float* giM, const _Float16* WBpack,
                                                const float* bhf, const float* bhb,
                                                const float* beta_w, const float* beta_b,
                                                float* Ball) {
    int half = blockIdx.x, n = blockIdx.y, dir = blockIdx.z;
    int tid = threadIdx.x;
    int w = tid >> 6;
    int lane = tid & 63;
    int quad = lane >> 4;
    int col  = lane & 15;

    __shared__ _Float16 Hhi[32*136];
    __shared__ _Float16 Hlo[32*136];
    __shared__ float    Hf[32*132];
    __shared__ float    bwT[4*132];
    for (int idx = tid; idx < 32*136; idx += 256) { Hhi[idx] = (_Float16)0.f; Hlo[idx] = (_Float16)0.f; }
    for (int idx = tid; idx < 32*132; idx += 256) Hf[idx] = 0.f;
    for (int idx = tid; idx < 512; idx += 256) { int k = idx >> 2, e = idx & 3; bwT[e*132 + k] = beta_w[k*NE + e]; }

    // resident weights: 48 frags = kt(4) x term(2) x nt(6), idx = kt*12 + term*6 + nt
    half8 WB[48];
    const half8* wsrc = (const half8*)(WBpack) + ((size_t)(dir*4 + w)*4)*12*64;
    #pragma unroll
    for (int f = 0; f < 48; ++f) WB[f] = wsrc[(size_t)f*64 + lane];

    const float* bh = dir ? bhb : bhf;
    float bhv[6];
    #pragma unroll
    for (int gt2 = 0; gt2 < 3; ++gt2) {
        bhv[gt2*2+0] = bh[gt2*128 + w*32 + col];
        bhv[gt2*2+1] = bh[gt2*128 + w*32 + col + 16];
    }
    const float* giBase = giM + (size_t)(dir*N_ + n)*NL*G3;

    int bseq = tid >> 3, bsub = tid & 7, bee = bsub & 3, bpart = bsub >> 2;
    float bbias = beta_b[bee];
    __syncthreads();

    for (int j = 0; j < NL; ++j) {
        floatx4 C[12];   // idx = Mt*6 + nt, nt = gt*2 + isub (gt: 0=r,1=z,2=n)
        #pragma unroll
        for (int Mt = 0; Mt < 2; ++Mt) {
            #pragma unroll
            for (int reg = 0; reg < 4; ++reg) {
                int seq = Mt*16 + quad*4 + reg;
                int p = half*32 + seq;
                int l = dir ? ((p + 63 - j) & 63) : ((p + j) & 63);
                const float* gl = giBase + l*G3 + w*32 + col;
                #pragma unroll
                for (int gt2 = 0; gt2 < 2; ++gt2)
                    #pragma unroll
                    for (int isub = 0; isub < 2; ++isub)
                        C[Mt*6 + gt2*2 + isub][reg] = gl[gt2*128 + isub*16] + bhv[gt2*2+isub];
                #pragma unroll
                for (int isub = 0; isub < 2; ++isub)
                    C[Mt*6 + 4 + isub][reg] = bhv[4+isub];
            }
        }
        #pragma unroll
        for (int kt = 0; kt < 4; ++kt) {
            half8 ahi[2], alo[2];
            #pragma unroll
            for (int Mt = 0; Mt < 2; ++Mt) {
                int off = (Mt*16 + col)*136 + kt*32 + quad*8;
                ahi[Mt] = *(const half8*)&Hhi[off];
                alo[Mt] = *(const half8*)&Hlo[off];
            }
            #pragma unroll
            for (int nt = 0; nt < 6; ++nt) {
                half8 bhi2 = WB[kt*12 + nt];
                half8 blo2 = WB[kt*12 + 6 + nt];
                #pragma unroll
                for (int Mt = 0; Mt < 2; ++Mt) {
                    C[Mt*6+nt] = __builtin_amdgcn_mfma_f32_16x16x32_f16(ahi[Mt], bhi2, C[Mt*6+nt], 0,0,0);
                    C[Mt*6+nt] = __builtin_amdgcn_mfma_f32_16x16x32_f16(alo[Mt], bhi2, C[Mt*6+nt], 0,0,0);
                    C[Mt*6+nt] = __builtin_amdgcn_mfma_f32_16x16x32_f16(ahi[Mt], blo2, C[Mt*6+nt], 0,0,0);
                }
            }
        }
        __syncthreads();   // all A-frag reads done before h writes

        #pragma unroll
        for (int Mt = 0; Mt < 2; ++Mt) {
            #pragma unroll
            for (int reg = 0; reg < 4; ++reg) {
                int seq = Mt*16 + quad*4 + reg;
                int p = half*32 + seq;
                int l = dir ? ((p + 63 - j) & 63) : ((p + j) & 63);
                const float* gl = giBase + l*G3 + 256 + w*32 + col;
                #pragma unroll
                for (int isub = 0; isub < 2; ++isub) {
                    int i = w*32 + isub*16 + col;
                    float r  = sigf(C[Mt*6 + isub][reg]);
                    float z  = sigf(C[Mt*6 + 2 + isub][reg]);
                    float nn = tanhf(gl[isub*16] + r*C[Mt*6 + 4 + isub][reg]);
                    float hold = Hf[seq*132 + i];
                    float hnew = (1.f - z)*nn + z*hold;
                    _Float16 hi = (_Float16)hnew;
                    _Float16 lo = (_Float16)(hnew - (float)hi);
                    Hf[seq*132 + i] = hnew;
                    Hhi[seq*136 + i] = hi;
                    Hlo[seq*136 + i] = lo;
                }
            }
        }
        __syncthreads();

        // beta head: 32 seqs x 4 e x 2 k-parts (strided, conflict-free)
        {
            float acc = 0.f;
            const float* hrow = &Hf[bseq*132];
            const float* brow = &bwT[bee*132];
            #pragma unroll 8
            for (int kk = 0; kk < 64; ++kk) {
                int k2 = bpart + 2*kk;
                acc += hrow[k2]*brow[k2];
            }
            acc += __shfl_xor(acc, 4);
            if (bpart == 0) {
                float bval = sigf(acc + bbias);
                int p = half*32 + bseq;
                Ball[((n*NL + p)*128 + 2*j + dir)*NE + bee] = bval;
            }
        }
    }
}

// stick-breaking -> reordered P_final[n][p][j][e]
__global__ __launch_bounds__(64) void k_P(const float* Ball, float* Pall) {
    int np = blockIdx.x;
    int tid = threadIdx.x;
    __shared__ float B[128][NE];
    __shared__ float Pf[128][NE];
    const float* src = Ball + np*128*NE;
    for (int idx = tid; idx < 128*NE; idx += 64) ((float*)B)[idx] = src[idx];
    __syncthreads();
    if (tid < NE) {
        int e = tid;
        float c = 1.f;
        for (int j2 = 0; j2 < 128; ++j2) {
            float bz = (j2 == 0 || j2 == 127) ? 0.f : B[j2][e];
            float bf = (j2 == 127) ? 1.f : bz;
            Pf[j2][e] = bf * c;
            c *= (1.f - bz);
        }
    }
    __syncthreads();
    float* dst = Pall + np*128*NE;
    for (int idx = tid; idx < 128*NE; idx += 64) {
        int j = idx >> 2, e = idx & 3;
        int jf = (j < 64) ? (2*(63 - j) + 1) : (2*(j - 64));
        dst[idx] = Pf[jf][e];
    }
}

// ---------------- head-GEMM precomputes ----------------
__global__ __launch_bounds__(256) void k_zmp(const float* M, const float* zw, float* zmp) {
    int cb = blockIdx.x, rb = blockIdx.y;
    int tid = threadIdx.x;
    __shared__ float At[32][E_];
    for (int idx = tid; idx < 32*E_; idx += 256) {
        int r = idx >> 7, k = idx & 127;
        At[r][k] = M[(rb*32 + r)*E_ + k];
    }
    __syncthreads();
    float acc[32];
    #pragma unroll
    for (int r = 0; r < 32; ++r) acc[r] = 0.f;
    int col = cb*256 + tid;
    #pragma unroll 4
    for (int k = 0; k < E_; ++k) {
        float w = zw[k*HD + col];
        #pragma unroll
        for (int r = 0; r < 32; ++r) acc[r] += At[r][k]*w;
    }
    #pragma unroll
    for (int r = 0; r < 32; ++r)
        zmp[(size_t)(rb*32 + r)*HD + col] = acc[r];
}

__global__ __launch_bounds__(256) void k_ip(const float* inv_all, const float* pa_all,
                                            const float* zw, const float* zb, float* zip) {
    int cb = blockIdx.x, rb = blockIdx.y;
    int tid = threadIdx.x;
    __shared__ float At[32][E_];
    for (int idx = tid; idx < 32*E_; idx += 256) {
        int r = idx >> 7, k = idx & 127;
        int row = rb*32 + r;
        At[r][k] = (k < 64) ? inv_all[row*RH + k] : pa_all[row*LE + (k - 64)];
    }
    __syncthreads();
    float acc[32];
    #pragma unroll
    for (int r = 0; r < 32; ++r) acc[r] = 0.f;
    int col = cb*256 + tid;
    #pragma unroll 4
    for (int k = 0; k < E_; ++k) {
        float w = zw[(192 + k)*HD + col];
        #pragma unroll
        for (int r = 0; r < 32; ++r) acc[r] += At[r][k]*w;
    }
    float b = zb[col];
    #pragma unroll
    for (int r = 0; r < 32; ++r)
        zip[(size_t)(rb*32 + r)*HD + col] = acc[r] + b;
}

__global__ __launch_bounds__(256) void k_mpsmall(const float* M, const float* uw, const float* dw,
                                                 float* ump, float* dmp) {
    int wg = blockIdx.x;
    int tid = threadIdx.x;
    __shared__ float Mt[64][E_];
    for (int idx = tid; idx < 64*E_; idx += 256)
        ((float*)Mt)[idx] = M[(size_t)wg*64*E_ + idx];
    __syncthreads();
    int r = tid >> 2, q = tid & 3;
    float au = 0.f, ad = 0.f;
    #pragma unroll 4
    for (int k = 0; k < E_; ++k) {
        float m = Mt[r][k];
        au += m*uw[k*NE + q];
        if (q < 2) ad += m*dw[k*2 + q];
    }
    int row = wg*64 + r;
    ump[row*NE + q] = au;
    if (q < 2) dmp[row*2 + q] = ad;
}

__global__ __launch_bounds__(256) void k_ipsmall(const float* inv_all, const float* pa_all,
                                                 const float* uw, const float* ub,
                                                 const float* dw, const float* db,
                                                 float* uip, float* dip) {
    int wg = blockIdx.x;
    int tid = threadIdx.x;
    __shared__ float At[64][E_];
    for (int idx = tid; idx < 64*E_; idx += 256) {
        int r = idx >> 7, k = idx & 127;
        int row = wg*64 + r;
        At[r][k] = (k < 64) ? inv_all[row*RH + k] : pa_all[row*LE + (k - 64)];
    }
    __syncthreads();
    int r = tid >> 2, q = tid & 3;
    float au = ub[q], ad = (q < 2) ? db[q] : 0.f;
    #pragma unroll 4
    for (int k = 0; k < E_; ++k) {
        float v = At[r][k];
        au += v*uw[(192 + k)*NE + q];
        if (q < 2) ad += v*dw[(192 + k)*2 + q];
    }
    int row = wg*64 + r;
    uip[row*NE + q] = au;
    if (q < 2) dip[row*2 + q] = ad;
}

// ---------------- per-step kernels ----------------

__global__ __launch_bounds__(256) void k_kern(const float* mp, const float* kernel_w,
                                              const float* kernel_b, float* kern_buf) {
    int tid = threadIdx.x;
    int col = blockIdx.x*32 + (tid & 31);
    int rg  = tid >> 5;
    __shared__ float ml[E_][68];
    for (int idx = tid; idx < N_*E_; idx += 256) {
        int nn2 = idx >> 7, e = idx & 127;
        ml[e][nn2] = mp[idx];
    }
    __syncthreads();
    float acc[8];
    #pragma unroll
    for (int r = 0; r < 8; ++r) acc[r] = 0.f;
    #pragma unroll 8
    for (int e = 0; e < E_; ++e) {
        float w = kernel_w[e*KCOLS + col];
        const float* mrow = &ml[e][rg*8];
        #pragma unroll
        for (int r = 0; r < 8; ++r) acc[r] += mrow[r]*w;
    }
    float kb = kernel_b[col];
    #pragma unroll
    for (int r = 0; r < 8; ++r)
        kern_buf[(size_t)(rg*8 + r)*KCOLS + col] = acc[r] + kb;
}

__global__ __launch_bounds__(256) void k_conv(const float* obs, const float* kern_buf,
                                              const float* conv_bias, float* h1_buf, int t) {
    int q_b = blockIdx.x, n_b = blockIdx.y;
    int tid = threadIdx.x;
    __shared__ float obs_l[D_*HW*20];
    __shared__ float kl[2304];
    const float4* op4 = (const float4*)(obs + (size_t)(t*N_ + n_b)*D_*HW*HW);
    #pragma unroll
    for (int k = 0; k < 4; ++k) {
        int idx = tid + k*256;
        int d = idx >> 6, rem = idx & 63;
        int y = rem >> 2, xq = rem & 3;
        *(float4*)&obs_l[d*320 + y*20 + xq*4] = op4[idx];
    }
    const float4* kp4 = (const float4*)(kern_buf + (size_t)n_b*KCOLS + q_b*2304);
    float4* kl4 = (float4*)kl;
    for (int idx = tid; idx < 576; idx += 256) kl4[idx] = kp4[idx];
    __syncthreads();

    int c = tid >> 4, y = tid & 15;
    float acc[16];
    #pragma unroll
    for (int x = 0; x < 16; ++x) acc[x] = 0.f;
    for (int d = 0; d < D_; ++d) {
        const float* kd = &kl[c*144 + d*9];
        #pragma unroll
        for (int ky = 0; ky < 3; ++ky) {
            int yy = y + ky - 1;
            if (yy < 0 || yy >= HW) continue;
            const float4* rs = (const float4*)&obs_l[(d*16 + yy)*20];
            float4 r0 = rs[0], r1 = rs[1], r2 = rs[2], r3 = rs[3];
            float row[18];
            row[0] = 0.f; row[17] = 0.f;
            row[1]=r0.x; row[2]=r0.y; row[3]=r0.z; row[4]=r0.w;
            row[5]=r1.x; row[6]=r1.y; row[7]=r1.z; row[8]=r1.w;
            row[9]=r2.x; row[10]=r2.y; row[11]=r2.z; row[12]=r2.w;
            row[13]=r3.x; row[14]=r3.y; row[15]=r3.z; row[16]=r3.w;
            float k0 = kd[ky*3], k1 = kd[ky*3+1], k2 = kd[ky*3+2];
            #pragma unroll
            for (int x = 0; x < 16; ++x)
                acc[x] += row[x]*k0 + row[x+1]*k1 + row[x+2]*k2;
        }
    }
    float bc = conv_bias[q_b*16 + c];
    float psum = 0.f;
    #pragma unroll
    for (int x = 0; x < 16; ++x) psum += fmaxf(acc[x] + bc, 0.f);
    psum += __shfl_xor(psum, 1);
    psum += __shfl_xor(psum, 2);
    psum += __shfl_xor(psum, 4);
    psum += __shfl_xor(psum, 8);
    if (y == 0) h1_buf[n_b*CH + q_b*16 + c] = psum;
}

__global__ __launch_bounds__(256) void k_heads(
    const float* h1_buf, const float* zmp, const float* zip,
    const float* ump, const float* uip, const float* dmp, const float* dip,
    const float* zw, const float* aw, const float* ab,
    const float* uw, const float* dw, const float* cw, const float* cb,
    const float* amask, const float* Pall, const float* M,
    float* mp_buf, int* p_cur, float* out, int t) {
    int n = blockIdx.x, tid = threadIdx.x;
    __shared__ float h1s[CH];
    __shared__ float z1s[HD];
    __shared__ float pla[A_][8];
    __shared__ float pc[32];
    __shared__ float la[A_];
    __shared__ float lu[NE];
    __shared__ float ld2[2];
    __shared__ float uvals[NE];
    __shared__ float dp[128];
    __shared__ float sc[1];
    __shared__ int   si[4];

    if (tid < CH) h1s[tid] = h1_buf[n*CH + tid];
    if (tid == 0) si[0] = p_cur[n];
    __syncthreads();
    int p = si[0];
    size_t ob = ((size_t)t*N_ + n)*OUTW;

    const float* zmpp = zmp + (size_t)(n*NL + p)*HD;
    const float* zipp = zip + (size_t)(t*N_ + n)*HD;
    #pragma unroll
    for (int hh = 0; hh < 2; ++hh) {
        int h = tid + hh*256;
        float acc = zmpp[h] + zipp[h];
        #pragma unroll 8
        for (int c = 0; c < CH; ++c) acc += h1s[c]*zw[(E_ + c)*HD + h];
        float v = fmaxf(acc, 0.f);
        z1s[h] = v;
        out[ob + 146 + h] = v;
    }
    __syncthreads();

    if (tid < 128) {
        int a2 = tid >> 3, part = tid & 7;
        float acc = 0.f;
        const float* z0 = z1s + part*64;
        #pragma unroll 8
        for (int h = 0; h < 64; ++h) acc += z0[h]*aw[(part*64 + h)*A_ + a2];
        pla[a2][part] = acc;
    } else if (tid < 160) {
        int part = tid - 128;
        float acc = 0.f;
        const float* z0 = z1s + part*16;
        #pragma unroll 8
        for (int h = 0; h < 16; ++h) acc += z0[h]*cw[part*16 + h];
        pc[part] = acc;
    } else if (tid < 164) {
        int e = tid - 160;
        float acc = ump[(n*NL + p)*NE + e] + uip[(t*N_ + n)*NE + e];
        #pragma unroll 8
        for (int c = 0; c < CH; ++c) acc += h1s[c]*uw[(E_ + c)*NE + e];
        lu[e] = acc;
    } else if (tid < 166) {
        int g = tid - 164;
        float acc = dmp[(n*NL + p)*2 + g] + dip[(t*N_ + n)*2 + g];
        #pragma unroll 8
        for (int c = 0; c < CH; ++c) acc += h1s[c]*dw[(E_ + c)*2 + g];
        ld2[g] = acc;
    }
    __syncthreads();
    if (tid < A_) {
        float acc = ab[tid];
        #pragma unroll
        for (int k = 0; k < 8; ++k) acc += pla[tid][k];
        la[tid] = acc;
    } else if (tid == 24) {
        float acc = cb[0];
        #pragma unroll
        for (int k = 0; k < 32; ++k) acc += pc[k];
        sc[0] = acc;
    }
    __syncthreads();

    if (tid == 0) {
        float mx = la[0];
        #pragma unroll
        for (int k2 = 1; k2 < A_; ++k2) mx = fmaxf(mx, la[k2]);
        float pr[A_]; float sum = 0.f;
        #pragma unroll
        for (int k2 = 0; k2 < A_; ++k2) { pr[k2] = expf(la[k2]-mx); sum += pr[k2]; }
        const float* am = amask + ((size_t)t*N_ + n)*A_;
        float best = -1.f; int bi2 = 0;
        #pragma unroll
        for (int k2 = 0; k2 < A_; ++k2) {
            float v = pr[k2]/sum * am[k2];
            out[ob + 1 + k2] = v;
            if (v > best) { best = v; bi2 = k2; }
        }
        out[ob + 0] = (float)bi2;
    } else if (tid == 1) {
        float mx = fmaxf(fmaxf(lu[0], lu[1]), fmaxf(lu[2], lu[3]));
        float ev[NE]; float s0 = 0.f;
        #pragma unroll
        for (int e = 0; e < NE; ++e) { ev[e] = expf(lu[e]-mx); s0 += ev[e]; }
        #pragma unroll
        for (int e = 0; e < NE; ++e) uvals[e] = ev[e]/s0;
    } else if (tid == 2) {
        float mx = fmaxf(ld2[0], ld2[1]);
        float e0 = expf(ld2[0]-mx), e1 = expf(ld2[1]-mx);
        float s0 = e0 + e1;
        out[ob + 660] = e0/s0;
        out[ob + 661] = e1/s0;
        int dg = (ld2[1] > ld2[0]) ? 1 : 0;
        si[2] = dg;
        out[ob + 662] = (float)dg;
    }
    __syncthreads();
    if (tid < 128) {
        const float* Pp = Pall + ((size_t)(n*NL + p)*128 + tid)*NE;
        float v = Pp[0]*uvals[0] + Pp[1]*uvals[1] + Pp[2]*uvals[2] + Pp[3]*uvals[3];
        dp[tid] = v;
        out[ob + 18 + tid] = v;
    }
    __syncthreads();
    if (tid == 0) {
        int dsel;
        if (si[2] == 1) {
            float best = dp[0]; dsel = 0;
            for (int j2 = 1; j2 < 128; ++j2) if (dp[j2] > best) { best = dp[j2]; dsel = j2; }
        } else dsel = 64;
        int pn = p + dsel - 64;
        pn = pn < 0 ? 0 : (pn > 63 ? 63 : pn);
        si[3] = pn;
        p_cur[n] = pn;
        out[ob + 17]  = (float)dsel;
        out[ob + 658] = (float)pn;
        out[ob + 659] = sc[0];
    }
    __syncthreads();
    if (tid < E_) {
        mp_buf[n*E_ + tid] = M[(n*NL + si[3])*E_ + tid];
    }
}

extern "C" void kernel_launch(void* const* d_in, const int* in_sizes, int n_in,
                              void* d_out, int out_size, void* d_ws, size_t ws_size,
                              hipStream_t stream) {
    (void)in_sizes; (void)n_in; (void)out_size; (void)ws_size;
    const int*   lines    = (const int*)  d_in[0];
    const float* obs      = (const float*)d_in[1];
    const float* invent   = (const float*)d_in[2];
    const int*   pa       = (const int*)  d_in[3];
    const float* amask    = (const float*)d_in[4];
    const int*   p0       = (const int*)  d_in[5];
    const float* emb_task = (const float*)d_in[6];
    const float* emb_low  = (const float*)d_in[7];
    const float* wi_f     = (const float*)d_in[8];
    const float* wh_f     = (const float*)d_in[9];
    const float* bi_f     = (const float*)d_in[10];
    const float* bh_f     = (const float*)d_in[11];
    const float* wi_b     = (const float*)d_in[12];
    const float* wh_b     = (const float*)d_in[13];
    const float* bi_b     = (const float*)d_in[14];
    const float* bh_b     = (const float*)d_in[15];
    const float* beta_w   = (const float*)d_in[16];
    const float* beta_b   = (const float*)d_in[17];
    const float* kernel_w = (const float*)d_in[18];
    const float* kernel_b = (const float*)d_in[19];
    const float* conv_b   = (const float*)d_in[20];
    const float* inv_w    = (const float*)d_in[21];
    const float* inv_b    = (const float*)d_in[22];
    const float* zw       = (const float*)d_in[23];
    const float* zb       = (const float*)d_in[24];
    const float* aw       = (const float*)d_in[25];
    const float* ab       = (const float*)d_in[26];
    const float* uw       = (const float*)d_in[27];
    const float* ub       = (const float*)d_in[28];
    const float* dw       = (const float*)d_in[29];
    const float* db       = (const float*)d_in[30];
    const float* cw       = (const float*)d_in[31];
    const float* cb       = (const float*)d_in[32];
    float* out = (float*)d_out;

    float* ws = (float*)d_ws;
    size_t off = 0;
    float* M        = ws + off; off += (size_t)N_*NL*E_;
    float* wiT4     = ws + off; off += 2*32*384*4;
    _Float16* WBpack = (_Float16*)(ws + off); off += (size_t)384*512/2;   // 384 frags x 512 halfs
    float* giM      = ws + off; off += (size_t)2*N_*NL*G3;
    float* Ball     = ws + off; off += (size_t)N_*NL*128*NE;
    float* Pall     = ws + off; off += (size_t)N_*NL*128*NE;
    float* inv_all  = ws + off; off += (size_t)T_*N_*RH;
    float* pa_all   = ws + off; off += (size_t)T_*N_*LE;
    float* kern_buf = ws + off; off += (size_t)N_*KCOLS;
    float* h1_buf   = ws + off; off += (size_t)N_*CH;
    float* mp_buf   = ws + off; off += (size_t)N_*E_;
    float* zmp      = ws + off; off += (size_t)N_*NL*HD;
    float* zip      = ws + off; off += (size_t)T_*N_*HD;
    float* ump      = ws + off; off += (size_t)N_*NL*NE;
    float* dmp      = ws + off; off += (size_t)N_*NL*2;
    float* uip      = ws + off; off += (size_t)T_*N_*NE;
    float* dip      = ws + off; off += (size_t)T_*N_*2;
    int*   p_cur    = (int*)(ws + off); off += 64;

    k_prep_M<<<N_*NL, 128, 0, stream>>>(lines, emb_task, M);
    k_prep_T4<<<768, 128, 0, stream>>>(wi_f, wi_b, wiT4);
    k_packW<<<384, 64, 0, stream>>>(wh_f, wh_b, WBpack);
    k_prep_misc<<<N_, 128, 0, stream>>>(p0, M, p_cur, mp_buf);
    k_prep_invpa<<<T_*N_, 64, 0, stream>>>(invent, inv_w, inv_b, pa, emb_low, inv_all, pa_all);
    k_giM<<<dim3(8, N_, 2), 384, 0, stream>>>(M, wiT4, bi_f, bi_b, giM);
    k_gru<<<dim3(2, N_, 2), 256, 0, stream>>>(giM, WBpack, bh_f, bh_b, beta_w, beta_b, Ball);
    k_P<<<N_*NL, 64, 0, stream>>>(Ball, Pall);
    k_zmp<<<dim3(2, 128), 256, 0, stream>>>(M, zw, zmp);
    k_ip<<<dim3(2, 64), 256, 0, stream>>>(inv_all, pa_all, zw, zb, zip);
    k_mpsmall<<<64, 256, 0, stream>>>(M, uw, dw, ump, dmp);
    k_ipsmall<<<32, 256, 0, stream>>>(inv_all, pa_all, uw, ub, dw, db, uip, dip);

    for (int t = 0; t < T_; ++t) {
        k_kern<<<KCOLS/32, 256, 0, stream>>>(mp_buf, kernel_w, kernel_b, kern_buf);
        k_conv<<<dim3(4, N_), 256, 0, stream>>>(obs, kern_buf, conv_b, h1_buf, t);
        k_heads<<<N_, 256, 0, stream>>>(h1_buf, zmp, zip, ump, uip, dmp, dip,
                                        zw, aw, ab, uw, dw, cw, cb,
                                        amask, Pall, M, mp_buf, p_cur, out, t);
    }
}